// Round 1
// baseline (737.055 us; speedup 1.0000x reference)
//
#include <hip/hip_runtime.h>

typedef __attribute__((ext_vector_type(8))) short short8;
typedef __attribute__((ext_vector_type(4))) float f32x4;

__device__ inline unsigned short f2b(float f) {
  unsigned int u = __builtin_bit_cast(unsigned int, f);
  u = (u + 0x7FFFu + ((u >> 16) & 1u)) >> 16;
  return (unsigned short)u;
}
__device__ inline float b2f(unsigned short s) {
  unsigned int u = ((unsigned int)s) << 16;
  return __builtin_bit_cast(float, u);
}

// async global->LDS, 16B per lane; LDS dest must be wave-uniform base (+lane*16 implicit)
__device__ inline void async16(const void* g, void* l) {
  __builtin_amdgcn_global_load_lds((__attribute__((address_space(1))) void*)(g),
                                   (__attribute__((address_space(3))) void*)(l), 16, 0, 0);
}

// ---------------- x fp32 -> bf16 ----------------
__global__ void cvt_x(const float4* __restrict__ x, ushort4* __restrict__ xb, int n4) {
  int i = blockIdx.x * blockDim.x + threadIdx.x;
  int stride = gridDim.x * blockDim.x;
  for (; i < n4; i += stride) {
    float4 v = x[i];
    ushort4 o;
    o.x = f2b(v.x); o.y = f2b(v.y); o.z = f2b(v.z); o.w = f2b(v.w);
    xb[i] = o;
  }
}

// ---------------- W_qkv [768][2304] -> Wt [2304(perm s,h,d)][768] bf16 ----------------
__global__ __launch_bounds__(256) void t_wqkv(const float* __restrict__ W, unsigned short* __restrict__ Wt) {
  __shared__ float tile[32][33];
  int j0 = blockIdx.x * 32, c0 = blockIdx.y * 32;
  int tx = threadIdx.x & 31, ty = threadIdx.x >> 5;
#pragma unroll
  for (int r = 0; r < 32; r += 8)
    tile[ty + r][tx] = W[(size_t)(c0 + ty + r) * 2304 + j0 + tx];
  __syncthreads();
#pragma unroll
  for (int r = 0; r < 32; r += 8) {
    int j = j0 + ty + r;
    int h = j / 288, rem = j - h * 288;
    int d = rem / 3, s = rem - d * 3;
    int jj = s * 768 + h * 96 + d;
    Wt[(size_t)jj * 768 + c0 + tx] = f2b(tile[tx][ty + r]);
  }
}

// ---------------- W_proj [768][768] -> Wt [768][768] bf16 (transpose) ----------------
__global__ __launch_bounds__(256) void t_wproj(const float* __restrict__ W, unsigned short* __restrict__ Wt) {
  __shared__ float tile[32][33];
  int j0 = blockIdx.x * 32, c0 = blockIdx.y * 32;
  int tx = threadIdx.x & 31, ty = threadIdx.x >> 5;
#pragma unroll
  for (int r = 0; r < 32; r += 8)
    tile[ty + r][tx] = W[(size_t)(c0 + ty + r) * 768 + j0 + tx];
  __syncthreads();
#pragma unroll
  for (int r = 0; r < 32; r += 8)
    Wt[(size_t)(j0 + ty + r) * 768 + c0 + tx] = f2b(tile[tx][ty + r]);
}

// ---------------- GEMM1: qkv = xb @ Wqkv, scatter to Q/K/V [b][h][n][96] bf16 ----------------
__global__ __launch_bounds__(256) void gemm_qkv(
    const unsigned short* __restrict__ A, const unsigned short* __restrict__ Bt,
    unsigned short* __restrict__ Q, unsigned short* __restrict__ Kd, unsigned short* __restrict__ V) {
  __shared__ __align__(16) unsigned short As[128 * 64];
  __shared__ __align__(16) unsigned short Bs[128 * 64];
  const int tid = threadIdx.x;
  const int wave = tid >> 6, lane = tid & 63;
  const int mlane = lane & 15, quad = lane >> 4;
  const int m0 = blockIdx.x * 128, n0 = blockIdx.y * 128;
  const int wm = (wave >> 1) * 64, wn = (wave & 1) * 64;
  f32x4 acc[4][4] = {};
  for (int k0 = 0; k0 < 768; k0 += 64) {
    __syncthreads();
#pragma unroll
    for (int t = 0; t < 4; ++t) {
      int ebase = t * 256 + (wave << 6);
      int e = ebase + lane;
      int row = e >> 3, c8 = e & 7;
      async16(A + (size_t)(m0 + row) * 768 + k0 + c8 * 8, As + ebase * 8);
      async16(Bt + (size_t)(n0 + row) * 768 + k0 + c8 * 8, Bs + ebase * 8);
    }
    __syncthreads();
#pragma unroll
    for (int kk = 0; kk < 64; kk += 32) {
      short8 a[4], b[4];
#pragma unroll
      for (int f = 0; f < 4; ++f)
        a[f] = *(const short8*)&As[(wm + f * 16 + mlane) * 64 + kk + quad * 8];
#pragma unroll
      for (int f = 0; f < 4; ++f)
        b[f] = *(const short8*)&Bs[(wn + f * 16 + mlane) * 64 + kk + quad * 8];
#pragma unroll
      for (int i = 0; i < 4; ++i)
#pragma unroll
        for (int j = 0; j < 4; ++j)
          acc[i][j] = __builtin_amdgcn_mfma_f32_16x16x32_bf16(a[i], b[j], acc[i][j], 0, 0, 0);
    }
  }
  const int bb = m0 >> 12;
  const int nb = (m0 & 4095) + wm + quad * 4;
#pragma unroll
  for (int fn = 0; fn < 4; ++fn) {
    int jj = n0 + wn + fn * 16 + mlane;
    int s = jj / 768;
    int hd = jj - s * 768;
    int h = hd / 96;
    int d = hd - h * 96;
    unsigned short* dst = (s == 0) ? Q : (s == 1) ? Kd : V;
    size_t colbase = ((size_t)(bb * 8 + h) * 4096) * 96 + d;
#pragma unroll
    for (int fm = 0; fm < 4; ++fm) {
      int n = nb + fm * 16;
#pragma unroll
      for (int r = 0; r < 4; ++r)
        dst[colbase + (size_t)(n + r) * 96] = f2b(acc[fm][fn][r]);
    }
  }
}

// ---------------- sum of squares over n per (b,h,d) for Q and K ----------------
__global__ __launch_bounds__(256) void sumsq_qk(
    const unsigned short* __restrict__ Q, const unsigned short* __restrict__ Kd,
    float* __restrict__ sq, float* __restrict__ sk) {
  int bh = blockIdx.x, chunk = blockIdx.y;
  int t = threadIdx.x;
  __shared__ float lq[96], lk[96];
  if (t < 96) { lq[t] = 0.f; lk[t] = 0.f; }
  __syncthreads();
  int c = t % 48, rg = t / 48;
  if (rg < 5) {
    const unsigned int* qp = (const unsigned int*)(Q + (size_t)bh * 4096 * 96);
    const unsigned int* kp = (const unsigned int*)(Kd + (size_t)bh * 4096 * 96);
    int base = chunk * 256;
    float aq0 = 0, aq1 = 0, ak0 = 0, ak1 = 0;
    for (int n = rg; n < 256; n += 5) {
      unsigned int qv = qp[(size_t)(base + n) * 48 + c];
      unsigned int kv = kp[(size_t)(base + n) * 48 + c];
      float q0 = b2f(qv & 0xffff), q1 = b2f(qv >> 16);
      float k0 = b2f(kv & 0xffff), k1 = b2f(kv >> 16);
      aq0 += q0 * q0; aq1 += q1 * q1; ak0 += k0 * k0; ak1 += k1 * k1;
    }
    atomicAdd(&lq[2 * c], aq0); atomicAdd(&lq[2 * c + 1], aq1);
    atomicAdd(&lk[2 * c], ak0); atomicAdd(&lk[2 * c + 1], ak1);
  }
  __syncthreads();
  if (t < 96) {
    atomicAdd(&sq[bh * 96 + t], lq[t]);
    atomicAdd(&sk[bh * 96 + t], lk[t]);
  }
}

// ---------------- attn: S = Q^T K (per b,h), normalize, softmax, write P bf16 [bh][96][96] ----------------
__global__ __launch_bounds__(256) void attn_softmax(
    const unsigned short* __restrict__ Q, const unsigned short* __restrict__ Kd,
    const float* __restrict__ sq, const float* __restrict__ sk,
    const float* __restrict__ temp, unsigned short* __restrict__ P) {
  int bh = blockIdx.x;
  int h = bh & 7;
  __shared__ __align__(16) unsigned short QT[96 * 72];
  __shared__ __align__(16) unsigned short KT[96 * 72];
  __shared__ float S[96 * 100];
  __shared__ float rk[96];
  int t = threadIdx.x;
  int wave = t >> 6, lane = t & 63, mlane = lane & 15, quad = lane >> 4;
  int wrow = (wave >> 1) * 48, wcol = (wave & 1) * 48;
  f32x4 acc[3][3] = {};
  const unsigned int* qp = (const unsigned int*)(Q + (size_t)bh * 4096 * 96);
  const unsigned int* kp = (const unsigned int*)(Kd + (size_t)bh * 4096 * 96);
  int c = t % 48, rg = t / 48;
  for (int n0 = 0; n0 < 4096; n0 += 64) {
    __syncthreads();
    if (rg < 5) {
      for (int n = rg; n < 64; n += 5) {
        unsigned int qv = qp[(size_t)(n0 + n) * 48 + c];
        unsigned int kv = kp[(size_t)(n0 + n) * 48 + c];
        QT[(2 * c) * 72 + n] = (unsigned short)(qv & 0xffff);
        QT[(2 * c + 1) * 72 + n] = (unsigned short)(qv >> 16);
        KT[(2 * c) * 72 + n] = (unsigned short)(kv & 0xffff);
        KT[(2 * c + 1) * 72 + n] = (unsigned short)(kv >> 16);
      }
    }
    __syncthreads();
#pragma unroll
    for (int kk = 0; kk < 64; kk += 32) {
      short8 a[3], b[3];
#pragma unroll
      for (int f = 0; f < 3; ++f)
        a[f] = *(const short8*)&QT[(wrow + f * 16 + mlane) * 72 + kk + quad * 8];
#pragma unroll
      for (int f = 0; f < 3; ++f)
        b[f] = *(const short8*)&KT[(wcol + f * 16 + mlane) * 72 + kk + quad * 8];
#pragma unroll
      for (int i = 0; i < 3; ++i)
#pragma unroll
        for (int j = 0; j < 3; ++j)
          acc[i][j] = __builtin_amdgcn_mfma_f32_16x16x32_bf16(a[i], b[j], acc[i][j], 0, 0, 0);
    }
  }
#pragma unroll
  for (int i = 0; i < 3; ++i)
#pragma unroll
    for (int j = 0; j < 3; ++j)
#pragma unroll
      for (int r = 0; r < 4; ++r)
        S[(wrow + i * 16 + quad * 4 + r) * 100 + wcol + j * 16 + mlane] = acc[i][j][r];
  if (t < 96) rk[t] = rsqrtf(sk[bh * 96 + t]);
  __syncthreads();
  if (t < 96) {
    int d = t;
    float rq = rsqrtf(sq[bh * 96 + d]);
    float tm = temp[h];
    float mx = -1e30f;
    for (int e = 0; e < 96; ++e) {
      float v = S[d * 100 + e] * rq * rk[e] * tm;
      S[d * 100 + e] = v;
      mx = fmaxf(mx, v);
    }
    float sum = 0.f;
    for (int e = 0; e < 96; ++e) {
      float v = expf(S[d * 100 + e] - mx);
      S[d * 100 + e] = v;
      sum += v;
    }
    float inv = 1.0f / sum;
    for (int e = 0; e < 96; ++e)
      P[(size_t)bh * 9216 + d * 96 + e] = f2b(S[d * 100 + e] * inv);
  }
}

// ---------------- y = V @ P^T per (b,h): y[b][n][h*96+d] bf16 ----------------
__global__ __launch_bounds__(256) void gemm_pv(
    const unsigned short* __restrict__ V, const unsigned short* __restrict__ P,
    unsigned short* __restrict__ y) {
  int bh = blockIdx.y;
  int b = bh >> 3, h = bh & 7;
  int m0 = blockIdx.x * 128;
  int t = threadIdx.x, wave = t >> 6, lane = t & 63, mlane = lane & 15, quad = lane >> 4;
  const unsigned short* Vb = V + (size_t)bh * 4096 * 96;
  const unsigned short* Pb = P + (size_t)bh * 9216;
  f32x4 acc[2][6] = {};
#pragma unroll
  for (int kk = 0; kk < 96; kk += 32) {
    short8 a[2], bfr[6];
#pragma unroll
    for (int i = 0; i < 2; ++i)
      a[i] = *(const short8*)&Vb[(size_t)(m0 + wave * 32 + i * 16 + mlane) * 96 + kk + quad * 8];
#pragma unroll
    for (int j = 0; j < 6; ++j)
      bfr[j] = *(const short8*)&Pb[(j * 16 + mlane) * 96 + kk + quad * 8];
#pragma unroll
    for (int i = 0; i < 2; ++i)
#pragma unroll
      for (int j = 0; j < 6; ++j)
        acc[i][j] = __builtin_amdgcn_mfma_f32_16x16x32_bf16(a[i], bfr[j], acc[i][j], 0, 0, 0);
  }
#pragma unroll
  for (int i = 0; i < 2; ++i) {
    int n = m0 + wave * 32 + i * 16 + quad * 4;
#pragma unroll
    for (int j = 0; j < 6; ++j) {
      int d = j * 16 + mlane;
#pragma unroll
      for (int r = 0; r < 4; ++r)
        y[((size_t)b * 4096 + n + r) * 768 + h * 96 + d] = f2b(acc[i][j][r]);
    }
  }
}

// ---------------- proj: out = y @ Wp + bias (fp32 out) ----------------
__global__ __launch_bounds__(256) void gemm_proj(
    const unsigned short* __restrict__ A, const unsigned short* __restrict__ Bt,
    const float* __restrict__ bias, float* __restrict__ out) {
  __shared__ __align__(16) unsigned short As[128 * 64];
  __shared__ __align__(16) unsigned short Bs[128 * 64];
  const int tid = threadIdx.x;
  const int wave = tid >> 6, lane = tid & 63;
  const int mlane = lane & 15, quad = lane >> 4;
  const int m0 = blockIdx.x * 128, n0 = blockIdx.y * 128;
  const int wm = (wave >> 1) * 64, wn = (wave & 1) * 64;
  f32x4 acc[4][4] = {};
  for (int k0 = 0; k0 < 768; k0 += 64) {
    __syncthreads();
#pragma unroll
    for (int t = 0; t < 4; ++t) {
      int ebase = t * 256 + (wave << 6);
      int e = ebase + lane;
      int row = e >> 3, c8 = e & 7;
      async16(A + (size_t)(m0 + row) * 768 + k0 + c8 * 8, As + ebase * 8);
      async16(Bt + (size_t)(n0 + row) * 768 + k0 + c8 * 8, Bs + ebase * 8);
    }
    __syncthreads();
#pragma unroll
    for (int kk = 0; kk < 64; kk += 32) {
      short8 a[4], b[4];
#pragma unroll
      for (int f = 0; f < 4; ++f)
        a[f] = *(const short8*)&As[(wm + f * 16 + mlane) * 64 + kk + quad * 8];
#pragma unroll
      for (int f = 0; f < 4; ++f)
        b[f] = *(const short8*)&Bs[(wn + f * 16 + mlane) * 64 + kk + quad * 8];
#pragma unroll
      for (int i = 0; i < 4; ++i)
#pragma unroll
        for (int j = 0; j < 4; ++j)
          acc[i][j] = __builtin_amdgcn_mfma_f32_16x16x32_bf16(a[i], b[j], acc[i][j], 0, 0, 0);
    }
  }
#pragma unroll
  for (int fn = 0; fn < 4; ++fn) {
    int col = n0 + wn + fn * 16 + mlane;
    float bv = bias[col];
#pragma unroll
    for (int fm = 0; fm < 4; ++fm) {
      int m = m0 + wm + fm * 16 + quad * 4;
#pragma unroll
      for (int r = 0; r < 4; ++r)
        out[(size_t)(m + r) * 768 + col] = acc[fm][fn][r] + bv;
    }
  }
}

extern "C" void kernel_launch(void* const* d_in, const int* in_sizes, int n_in,
                              void* d_out, int out_size, void* d_ws, size_t ws_size,
                              hipStream_t stream) {
  const float* x = (const float*)d_in[0];
  const float* Wqkv = (const float*)d_in[1];
  const float* Wproj = (const float*)d_in[2];
  const float* bias = (const float*)d_in[3];
  const float* temp = (const float*)d_in[4];
  float* out = (float*)d_out;

  char* ws = (char*)d_ws;
  size_t off = 0;
  auto alloc = [&](size_t bytes) -> void* {
    void* p = ws + off;
    off += (bytes + 255) & ~(size_t)255;
    return p;
  };
  unsigned short* xb = (unsigned short*)alloc(32768ull * 768 * 2);  // reused as y after gemm_qkv
  unsigned short* Wtq = (unsigned short*)alloc(2304ull * 768 * 2);
  unsigned short* Wtp = (unsigned short*)alloc(768ull * 768 * 2);
  unsigned short* Q = (unsigned short*)alloc(64ull * 4096 * 96 * 2);
  unsigned short* Kd = (unsigned short*)alloc(64ull * 4096 * 96 * 2);
  unsigned short* V = (unsigned short*)alloc(64ull * 4096 * 96 * 2);
  float* sq = (float*)alloc(64 * 96 * 4);
  float* sk = (float*)alloc(64 * 96 * 4);
  unsigned short* P = (unsigned short*)alloc(64ull * 9216 * 2);
  (void)off; (void)ws_size; (void)in_sizes; (void)n_in; (void)out_size;

  cvt_x<<<4096, 256, 0, stream>>>((const float4*)x, (ushort4*)xb, 32768 * 768 / 4);
  t_wqkv<<<dim3(72, 24), 256, 0, stream>>>(Wqkv, Wtq);
  t_wproj<<<dim3(24, 24), 256, 0, stream>>>(Wproj, Wtp);
  gemm_qkv<<<dim3(256, 18), 256, 0, stream>>>(xb, Wtq, Q, Kd, V);
  hipMemsetAsync(sq, 0, 64 * 96 * 4, stream);
  hipMemsetAsync(sk, 0, 64 * 96 * 4, stream);
  sumsq_qk<<<dim3(64, 16), 256, 0, stream>>>(Q, Kd, sq, sk);
  attn_softmax<<<64, 256, 0, stream>>>(Q, Kd, sq, sk, temp, P);
  gemm_pv<<<dim3(32, 64), 256, 0, stream>>>(V, P, xb /*y*/);
  gemm_proj<<<dim3(256, 6), 256, 0, stream>>>(xb /*y*/, Wtp, bias, out);
}

// Round 2
// 550.412 us; speedup vs baseline: 1.3391x; 1.3391x over previous
//
#include <hip/hip_runtime.h>

typedef __attribute__((ext_vector_type(8))) short short8;
typedef __attribute__((ext_vector_type(4))) float f32x4;

__device__ inline unsigned short f2b(float f) {
  unsigned int u = __builtin_bit_cast(unsigned int, f);
  u = (u + 0x7FFFu + ((u >> 16) & 1u)) >> 16;
  return (unsigned short)u;
}
__device__ inline float b2f(unsigned short s) {
  unsigned int u = ((unsigned int)s) << 16;
  return __builtin_bit_cast(float, u);
}

__device__ inline void async16(const void* g, void* l) {
  __builtin_amdgcn_global_load_lds((__attribute__((address_space(1))) void*)(g),
                                   (__attribute__((address_space(3))) void*)(l), 16, 0, 0);
}

// ---------------- x fp32 -> bf16 ----------------
__global__ void cvt_x(const float4* __restrict__ x, ushort4* __restrict__ xb, int n4) {
  int i = blockIdx.x * blockDim.x + threadIdx.x;
  int stride = gridDim.x * blockDim.x;
  for (; i < n4; i += stride) {
    float4 v = x[i];
    ushort4 o;
    o.x = f2b(v.x); o.y = f2b(v.y); o.z = f2b(v.z); o.w = f2b(v.w);
    xb[i] = o;
  }
}

// ---------------- W_qkv [768][2304] -> Wt [2304(perm s,h,d)][768] bf16 ----------------
__global__ __launch_bounds__(256) void t_wqkv(const float* __restrict__ W, unsigned short* __restrict__ Wt) {
  __shared__ float tile[32][33];
  int j0 = blockIdx.x * 32, c0 = blockIdx.y * 32;
  int tx = threadIdx.x & 31, ty = threadIdx.x >> 5;
#pragma unroll
  for (int r = 0; r < 32; r += 8)
    tile[ty + r][tx] = W[(size_t)(c0 + ty + r) * 2304 + j0 + tx];
  __syncthreads();
#pragma unroll
  for (int r = 0; r < 32; r += 8) {
    int j = j0 + ty + r;
    int h = j / 288, rem = j - h * 288;
    int d = rem / 3, s = rem - d * 3;
    int jj = s * 768 + h * 96 + d;
    Wt[(size_t)jj * 768 + c0 + tx] = f2b(tile[tx][ty + r]);
  }
}

// ---------------- W_proj [768][768] -> Wt [768][768] bf16 (transpose) ----------------
__global__ __launch_bounds__(256) void t_wproj(const float* __restrict__ W, unsigned short* __restrict__ Wt) {
  __shared__ float tile[32][33];
  int j0 = blockIdx.x * 32, c0 = blockIdx.y * 32;
  int tx = threadIdx.x & 31, ty = threadIdx.x >> 5;
#pragma unroll
  for (int r = 0; r < 32; r += 8)
    tile[ty + r][tx] = W[(size_t)(c0 + ty + r) * 768 + j0 + tx];
  __syncthreads();
#pragma unroll
  for (int r = 0; r < 32; r += 8)
    Wt[(size_t)(j0 + ty + r) * 768 + c0 + tx] = f2b(tile[tx][ty + r]);
}

// ---------------- GEMM1: qkv = xb @ Wqkv, scatter to Q/K/V [b][h][n][96] bf16 ----------------
__global__ __launch_bounds__(256) void gemm_qkv(
    const unsigned short* __restrict__ A, const unsigned short* __restrict__ Bt,
    unsigned short* __restrict__ Q, unsigned short* __restrict__ Kd, unsigned short* __restrict__ V) {
  __shared__ __align__(16) unsigned short As[128 * 64];
  __shared__ __align__(16) unsigned short Bs[128 * 64];
  const int tid = threadIdx.x;
  const int wave = tid >> 6, lane = tid & 63;
  const int mlane = lane & 15, quad = lane >> 4;
  const int m0 = blockIdx.x * 128, n0 = blockIdx.y * 128;
  const int wm = (wave >> 1) * 64, wn = (wave & 1) * 64;
  f32x4 acc[4][4] = {};
  for (int k0 = 0; k0 < 768; k0 += 64) {
    __syncthreads();
#pragma unroll
    for (int t = 0; t < 4; ++t) {
      int ebase = t * 256 + (wave << 6);
      int e = ebase + lane;
      int row = e >> 3, c8 = e & 7;
      async16(A + (size_t)(m0 + row) * 768 + k0 + c8 * 8, As + ebase * 8);
      async16(Bt + (size_t)(n0 + row) * 768 + k0 + c8 * 8, Bs + ebase * 8);
    }
    __syncthreads();
#pragma unroll
    for (int kk = 0; kk < 64; kk += 32) {
      short8 a[4], b[4];
#pragma unroll
      for (int f = 0; f < 4; ++f)
        a[f] = *(const short8*)&As[(wm + f * 16 + mlane) * 64 + kk + quad * 8];
#pragma unroll
      for (int f = 0; f < 4; ++f)
        b[f] = *(const short8*)&Bs[(wn + f * 16 + mlane) * 64 + kk + quad * 8];
#pragma unroll
      for (int i = 0; i < 4; ++i)
#pragma unroll
        for (int j = 0; j < 4; ++j)
          acc[i][j] = __builtin_amdgcn_mfma_f32_16x16x32_bf16(a[i], b[j], acc[i][j], 0, 0, 0);
    }
  }
  const int bb = m0 >> 12;
  const int nb = (m0 & 4095) + wm + quad * 4;
#pragma unroll
  for (int fn = 0; fn < 4; ++fn) {
    int jj = n0 + wn + fn * 16 + mlane;
    int s = jj / 768;
    int hd = jj - s * 768;
    int h = hd / 96;
    int d = hd - h * 96;
    unsigned short* dst = (s == 0) ? Q : (s == 1) ? Kd : V;
    size_t colbase = ((size_t)(bb * 8 + h) * 4096) * 96 + d;
#pragma unroll
    for (int fm = 0; fm < 4; ++fm) {
      int n = nb + fm * 16;
#pragma unroll
      for (int r = 0; r < 4; ++r)
        dst[colbase + (size_t)(n + r) * 96] = f2b(acc[fm][fn][r]);
    }
  }
}

// ---------------- sum of squares over n per (b,h,d) for Q and K ----------------
__global__ __launch_bounds__(256) void sumsq_qk(
    const unsigned short* __restrict__ Q, const unsigned short* __restrict__ Kd,
    float* __restrict__ sq, float* __restrict__ sk) {
  int bh = blockIdx.x, chunk = blockIdx.y;
  int t = threadIdx.x;
  __shared__ float lq[96], lk[96];
  if (t < 96) { lq[t] = 0.f; lk[t] = 0.f; }
  __syncthreads();
  int c = t % 48, rg = t / 48;
  if (rg < 5) {
    const unsigned int* qp = (const unsigned int*)(Q + (size_t)bh * 4096 * 96);
    const unsigned int* kp = (const unsigned int*)(Kd + (size_t)bh * 4096 * 96);
    int base = chunk * 256;
    float aq0 = 0, aq1 = 0, ak0 = 0, ak1 = 0;
    for (int n = rg; n < 256; n += 5) {
      unsigned int qv = qp[(size_t)(base + n) * 48 + c];
      unsigned int kv = kp[(size_t)(base + n) * 48 + c];
      float q0 = b2f(qv & 0xffff), q1 = b2f(qv >> 16);
      float k0 = b2f(kv & 0xffff), k1 = b2f(kv >> 16);
      aq0 += q0 * q0; aq1 += q1 * q1; ak0 += k0 * k0; ak1 += k1 * k1;
    }
    atomicAdd(&lq[2 * c], aq0); atomicAdd(&lq[2 * c + 1], aq1);
    atomicAdd(&lk[2 * c], ak0); atomicAdd(&lk[2 * c + 1], ak1);
  }
  __syncthreads();
  if (t < 96) {
    atomicAdd(&sq[bh * 96 + t], lq[t]);
    atomicAdd(&sk[bh * 96 + t], lk[t]);
  }
}

// ---------------- attn split-K partial: Spart[bh][chunk][96][96] fp32 ----------------
__global__ __launch_bounds__(256) void attn_partial(
    const unsigned short* __restrict__ Q, const unsigned short* __restrict__ Kd,
    float* __restrict__ Spart) {
  int chunk = blockIdx.x;  // 16 chunks of 256 rows
  int bh = blockIdx.y;
  __shared__ __align__(16) unsigned short QT[96 * 72];
  __shared__ __align__(16) unsigned short KT[96 * 72];
  int t = threadIdx.x;
  int wave = t >> 6, lane = t & 63, mlane = lane & 15, quad = lane >> 4;
  int wrow = (wave >> 1) * 48, wcol = (wave & 1) * 48;
  f32x4 acc[3][3] = {};
  const unsigned int* qp = (const unsigned int*)(Q + (size_t)bh * 4096 * 96);
  const unsigned int* kp = (const unsigned int*)(Kd + (size_t)bh * 4096 * 96);
  int c = t % 48, rg = t / 48;
  int nbeg = chunk * 256;
  for (int n0 = nbeg; n0 < nbeg + 256; n0 += 64) {
    __syncthreads();
    if (rg < 5) {
      for (int n = rg; n < 64; n += 5) {
        unsigned int qv = qp[(size_t)(n0 + n) * 48 + c];
        unsigned int kv = kp[(size_t)(n0 + n) * 48 + c];
        QT[(2 * c) * 72 + n] = (unsigned short)(qv & 0xffff);
        QT[(2 * c + 1) * 72 + n] = (unsigned short)(qv >> 16);
        KT[(2 * c) * 72 + n] = (unsigned short)(kv & 0xffff);
        KT[(2 * c + 1) * 72 + n] = (unsigned short)(kv >> 16);
      }
    }
    __syncthreads();
#pragma unroll
    for (int kk = 0; kk < 64; kk += 32) {
      short8 a[3], b[3];
#pragma unroll
      for (int f = 0; f < 3; ++f)
        a[f] = *(const short8*)&QT[(wrow + f * 16 + mlane) * 72 + kk + quad * 8];
#pragma unroll
      for (int f = 0; f < 3; ++f)
        b[f] = *(const short8*)&KT[(wcol + f * 16 + mlane) * 72 + kk + quad * 8];
#pragma unroll
      for (int i = 0; i < 3; ++i)
#pragma unroll
        for (int j = 0; j < 3; ++j)
          acc[i][j] = __builtin_amdgcn_mfma_f32_16x16x32_bf16(a[i], b[j], acc[i][j], 0, 0, 0);
    }
  }
  float* dst = Spart + ((size_t)bh * 16 + chunk) * 9216;
#pragma unroll
  for (int i = 0; i < 3; ++i)
#pragma unroll
    for (int j = 0; j < 3; ++j)
#pragma unroll
      for (int r = 0; r < 4; ++r)
        dst[(wrow + i * 16 + quad * 4 + r) * 96 + wcol + j * 16 + mlane] = acc[i][j][r];
}

// ---------------- finalize: sum partials, normalize, softmax, write P bf16 ----------------
__global__ __launch_bounds__(256) void attn_finalize(
    const float* __restrict__ Spart, const float* __restrict__ sq,
    const float* __restrict__ sk, const float* __restrict__ temp,
    unsigned short* __restrict__ P) {
  int bh = blockIdx.x, h = bh & 7;
  __shared__ float S[9216];
  __shared__ float rk[96];
  int t = threadIdx.x;
  const float* base = Spart + (size_t)bh * 16 * 9216;
  for (int i = t; i < 9216; i += 256) {
    float s = 0.f;
#pragma unroll
    for (int c2 = 0; c2 < 16; ++c2) s += base[(size_t)c2 * 9216 + i];
    S[i] = s;
  }
  if (t < 96) rk[t] = rsqrtf(sk[bh * 96 + t]);
  __syncthreads();
  if (t < 96) {
    int d = t;
    float rq = rsqrtf(sq[bh * 96 + d]);
    float tm = temp[h];
    float mx = -1e30f;
    for (int e = 0; e < 96; ++e) {
      float v = S[d * 96 + e] * rq * rk[e] * tm;
      S[d * 96 + e] = v;
      mx = fmaxf(mx, v);
    }
    float sum = 0.f;
    for (int e = 0; e < 96; ++e) {
      float v = expf(S[d * 96 + e] - mx);
      S[d * 96 + e] = v;
      sum += v;
    }
    float inv = 1.0f / sum;
    for (int e = 0; e < 96; ++e)
      P[(size_t)bh * 9216 + d * 96 + e] = f2b(S[d * 96 + e] * inv);
  }
}

// ---------------- y = V @ P^T per (b,h): y[b][n][h*96+d] bf16 ----------------
__global__ __launch_bounds__(256) void gemm_pv(
    const unsigned short* __restrict__ V, const unsigned short* __restrict__ P,
    unsigned short* __restrict__ y) {
  int bh = blockIdx.y;
  int b = bh >> 3, h = bh & 7;
  int m0 = blockIdx.x * 128;
  int t = threadIdx.x, wave = t >> 6, lane = t & 63, mlane = lane & 15, quad = lane >> 4;
  const unsigned short* Vb = V + (size_t)bh * 4096 * 96;
  const unsigned short* Pb = P + (size_t)bh * 9216;
  f32x4 acc[2][6] = {};
#pragma unroll
  for (int kk = 0; kk < 96; kk += 32) {
    short8 a[2], bfr[6];
#pragma unroll
    for (int i = 0; i < 2; ++i)
      a[i] = *(const short8*)&Vb[(size_t)(m0 + wave * 32 + i * 16 + mlane) * 96 + kk + quad * 8];
#pragma unroll
    for (int j = 0; j < 6; ++j)
      bfr[j] = *(const short8*)&Pb[(j * 16 + mlane) * 96 + kk + quad * 8];
#pragma unroll
    for (int i = 0; i < 2; ++i)
#pragma unroll
      for (int j = 0; j < 6; ++j)
        acc[i][j] = __builtin_amdgcn_mfma_f32_16x16x32_bf16(a[i], bfr[j], acc[i][j], 0, 0, 0);
  }
#pragma unroll
  for (int i = 0; i < 2; ++i) {
    int n = m0 + wave * 32 + i * 16 + quad * 4;
#pragma unroll
    for (int j = 0; j < 6; ++j) {
      int d = j * 16 + mlane;
#pragma unroll
      for (int r = 0; r < 4; ++r)
        y[((size_t)b * 4096 + n + r) * 768 + h * 96 + d] = f2b(acc[i][j][r]);
    }
  }
}

// ---------------- proj: out = y @ Wp + bias (fp32 out) ----------------
__global__ __launch_bounds__(256) void gemm_proj(
    const unsigned short* __restrict__ A, const unsigned short* __restrict__ Bt,
    const float* __restrict__ bias, float* __restrict__ out) {
  __shared__ __align__(16) unsigned short As[128 * 64];
  __shared__ __align__(16) unsigned short Bs[128 * 64];
  const int tid = threadIdx.x;
  const int wave = tid >> 6, lane = tid & 63;
  const int mlane = lane & 15, quad = lane >> 4;
  const int m0 = blockIdx.x * 128, n0 = blockIdx.y * 128;
  const int wm = (wave >> 1) * 64, wn = (wave & 1) * 64;
  f32x4 acc[4][4] = {};
  for (int k0 = 0; k0 < 768; k0 += 64) {
    __syncthreads();
#pragma unroll
    for (int t = 0; t < 4; ++t) {
      int ebase = t * 256 + (wave << 6);
      int e = ebase + lane;
      int row = e >> 3, c8 = e & 7;
      async16(A + (size_t)(m0 + row) * 768 + k0 + c8 * 8, As + ebase * 8);
      async16(Bt + (size_t)(n0 + row) * 768 + k0 + c8 * 8, Bs + ebase * 8);
    }
    __syncthreads();
#pragma unroll
    for (int kk = 0; kk < 64; kk += 32) {
      short8 a[4], b[4];
#pragma unroll
      for (int f = 0; f < 4; ++f)
        a[f] = *(const short8*)&As[(wm + f * 16 + mlane) * 64 + kk + quad * 8];
#pragma unroll
      for (int f = 0; f < 4; ++f)
        b[f] = *(const short8*)&Bs[(wn + f * 16 + mlane) * 64 + kk + quad * 8];
#pragma unroll
      for (int i = 0; i < 4; ++i)
#pragma unroll
        for (int j = 0; j < 4; ++j)
          acc[i][j] = __builtin_amdgcn_mfma_f32_16x16x32_bf16(a[i], b[j], acc[i][j], 0, 0, 0);
    }
  }
#pragma unroll
  for (int fn = 0; fn < 4; ++fn) {
    int col = n0 + wn + fn * 16 + mlane;
    float bv = bias[col];
#pragma unroll
    for (int fm = 0; fm < 4; ++fm) {
      int m = m0 + wm + fm * 16 + quad * 4;
#pragma unroll
      for (int r = 0; r < 4; ++r)
        out[(size_t)(m + r) * 768 + col] = acc[fm][fn][r] + bv;
    }
  }
}

extern "C" void kernel_launch(void* const* d_in, const int* in_sizes, int n_in,
                              void* d_out, int out_size, void* d_ws, size_t ws_size,
                              hipStream_t stream) {
  const float* x = (const float*)d_in[0];
  const float* Wqkv = (const float*)d_in[1];
  const float* Wproj = (const float*)d_in[2];
  const float* bias = (const float*)d_in[3];
  const float* temp = (const float*)d_in[4];
  float* out = (float*)d_out;

  char* ws = (char*)d_ws;
  size_t off = 0;
  auto alloc = [&](size_t bytes) -> void* {
    void* p = ws + off;
    off += (bytes + 255) & ~(size_t)255;
    return p;
  };
  unsigned short* xb = (unsigned short*)alloc(32768ull * 768 * 2);  // reused as y after gemm_qkv
  unsigned short* Wtq = (unsigned short*)alloc(2304ull * 768 * 2);
  unsigned short* Wtp = (unsigned short*)alloc(768ull * 768 * 2);
  unsigned short* Q = (unsigned short*)alloc(64ull * 4096 * 96 * 2);
  unsigned short* Kd = (unsigned short*)alloc(64ull * 4096 * 96 * 2);
  unsigned short* V = (unsigned short*)alloc(64ull * 4096 * 96 * 2);
  float* sq = (float*)alloc(64 * 96 * 4);
  float* sk = (float*)alloc(64 * 96 * 4);
  unsigned short* P = (unsigned short*)alloc(64ull * 9216 * 2);
  (void)off; (void)ws_size; (void)in_sizes; (void)n_in; (void)out_size;

  // Spart (64*16*9216 fp32 = 37.75 MB) staged in d_out (100 MB), which is
  // only written by gemm_proj at the very end — stream-ordered, no race.
  float* Spart = out;

  cvt_x<<<4096, 256, 0, stream>>>((const float4*)x, (ushort4*)xb, 32768 * 768 / 4);
  t_wqkv<<<dim3(72, 24), 256, 0, stream>>>(Wqkv, Wtq);
  t_wproj<<<dim3(24, 24), 256, 0, stream>>>(Wproj, Wtp);
  gemm_qkv<<<dim3(256, 18), 256, 0, stream>>>(xb, Wtq, Q, Kd, V);
  hipMemsetAsync(sq, 0, 64 * 96 * 4, stream);
  hipMemsetAsync(sk, 0, 64 * 96 * 4, stream);
  sumsq_qk<<<dim3(64, 16), 256, 0, stream>>>(Q, Kd, sq, sk);
  attn_partial<<<dim3(16, 64), 256, 0, stream>>>(Q, Kd, Spart);
  attn_finalize<<<64, 256, 0, stream>>>(Spart, sq, sk, temp, P);
  gemm_pv<<<dim3(32, 64), 256, 0, stream>>>(V, P, xb /*y*/);
  gemm_proj<<<dim3(256, 6), 256, 0, stream>>>(xb /*y*/, Wtp, bias, out);
}